// Round 6
// baseline (147.545 us; speedup 1.0000x reference)
//
#include <hip/hip_runtime.h>

#define NTOK 16384
#define CD   256
#define NH   8
#define HD   32
#define SCALE 0.17677669529663687f

typedef float    f32x4 __attribute__((ext_vector_type(4)));
typedef _Float16 f16x8 __attribute__((ext_vector_type(8)));
typedef _Float16 f16x4 __attribute__((ext_vector_type(4)));

__device__ __forceinline__ int a_addr(int n, int c) {
  return n * 256 + ((((c >> 3) ^ (n & 7)) << 3) | (c & 7));
}

// ---------------------------------------------------------------------------
// Fused KV-projection + per-head context partials (fp16 MFMA).
//   ctx_h(b) = K_hᵀ V_h,  K = A Wkᵀ, V = A Wvᵀ
// Grid 512 = 8 mats x 64 chunks (256 rows) -> 2 blocks/CU for barrier overlap.
// Block 512 = 8 waves, wave = head. Partials -> Mpart (= d_out scratch).
// ---------------------------------------------------------------------------
__global__ __launch_bounds__(512, 2) void kvctx_kernel(
    const float* __restrict__ rgb, const float* __restrict__ xin,
    const float* __restrict__ Wr, const float* __restrict__ Wx,
    float* __restrict__ Mpart)
{
  __shared__ __align__(16) _Float16 Ah[2][32 * 256];
  __shared__ __align__(16) _Float16 KVl[8][64 * 40];

  const int bid   = blockIdx.x;
  const int mat   = bid >> 6;              // s*4 + b
  const int chunk = bid & 63;              // 256-row chunk
  const int s     = mat >> 2;
  const float* __restrict__ A =
      (s == 0 ? rgb : xin) + (size_t)(mat & 3) * (NTOK * CD) + (size_t)chunk * 256 * CD;
  const float* __restrict__ W = (s == 0 ? Wr : Wx);

  const int t    = threadIdx.x;
  const int lane = t & 63;
  const int h    = t >> 6;                 // wave index = head
  const int cm   = lane & 15;
  const int qq   = lane >> 4;

  f32x4 v[4];
  auto issue_loads = [&](int sl) {
#pragma unroll
    for (int i = 0; i < 4; ++i)
      v[i] = *(const f32x4*)(A + (size_t)(sl * 32 + i * 8 + h) * CD + lane * 4);
  };
  auto stage = [&](int buf) {
#pragma unroll
    for (int i = 0; i < 4; ++i) {
      const int n = i * 8 + h;
      const int c = lane * 4;
      f16x4 p;
#pragma unroll
      for (int j = 0; j < 4; ++j) p[j] = (_Float16)v[i][j];
      *(f16x4*)&Ah[buf][a_addr(n, c)] = p;
    }
  };

  issue_loads(0);
  f16x8 wfrag[4][8];
#pragma unroll
  for (int jt = 0; jt < 4; ++jt) {
    const int wrow = (jt < 2) ? (h * HD + jt * 16 + cm)
                              : (CD + h * HD + (jt - 2) * 16 + cm);
    const float* wp = W + (size_t)wrow * CD;
#pragma unroll
    for (int ct = 0; ct < 8; ++ct) {
      f32x4 w0 = *(const f32x4*)(wp + ct * 32 + qq * 8);
      f32x4 w1 = *(const f32x4*)(wp + ct * 32 + qq * 8 + 4);
      f16x8 f;
#pragma unroll
      for (int j = 0; j < 4; ++j) { f[j] = (_Float16)w0[j]; f[4 + j] = (_Float16)w1[j]; }
      wfrag[jt][ct] = f;
    }
  }
  stage(0);
  __syncthreads();

  f32x4 ctx[2][2];
#pragma unroll
  for (int i = 0; i < 2; ++i)
#pragma unroll
    for (int j = 0; j < 2; ++j) ctx[i][j] = (f32x4){0.f, 0.f, 0.f, 0.f};

  _Float16* KW = KVl[h];

#pragma unroll 1
  for (int sl = 0; sl < 8; ++sl) {
    const int cur = sl & 1;
    if (sl < 7) issue_loads(sl + 1);

    // GEMM1: KV[32 n x 64 j] = A_slab x Wᵀ
    f32x4 kv[2][4];
#pragma unroll
    for (int nt = 0; nt < 2; ++nt)
#pragma unroll
      for (int jt = 0; jt < 4; ++jt) kv[nt][jt] = (f32x4){0.f, 0.f, 0.f, 0.f};
#pragma unroll
    for (int ct = 0; ct < 8; ++ct) {
      f16x8 ah[2];
#pragma unroll
      for (int nt = 0; nt < 2; ++nt) {
        const int row = nt * 16 + cm;
        const int ad  = row * 256 + (((ct * 4 + qq) ^ (row & 7)) << 3);
        ah[nt] = *(const f16x8*)&Ah[cur][ad];
      }
#pragma unroll
      for (int nt = 0; nt < 2; ++nt)
#pragma unroll
        for (int jt = 0; jt < 4; ++jt)
          kv[nt][jt] = __builtin_amdgcn_mfma_f32_16x16x32_f16(ah[nt], wfrag[jt][ct], kv[nt][jt], 0, 0, 0);
    }

    // KV -> wave-private LDS, [j][n] layout
#pragma unroll
    for (int nt = 0; nt < 2; ++nt)
#pragma unroll
      for (int jt = 0; jt < 4; ++jt) {
        const int jj = jt * 16 + cm;
        const int ad = jj * 40 + nt * 16 + qq * 4;
        f16x4 p;
#pragma unroll
        for (int r = 0; r < 4; ++r) p[r] = (_Float16)kv[nt][jt][r];
        *(f16x4*)&KW[ad] = p;
      }

    // GEMM2: ctx[d][e] += Σ_n K[n,d] V[n,e]
    f16x8 kf[2], vf[2];
#pragma unroll
    for (int dt = 0; dt < 2; ++dt)
      kf[dt] = *(const f16x8*)&KW[(dt * 16 + cm) * 40 + qq * 8];
#pragma unroll
    for (int et = 0; et < 2; ++et)
      vf[et] = *(const f16x8*)&KW[(32 + et * 16 + cm) * 40 + qq * 8];
#pragma unroll
    for (int dt = 0; dt < 2; ++dt)
#pragma unroll
      for (int et = 0; et < 2; ++et)
        ctx[dt][et] = __builtin_amdgcn_mfma_f32_16x16x32_f16(kf[dt], vf[et], ctx[dt][et], 0, 0, 0);

    if (sl < 7) {
      stage(cur ^ 1);
      __syncthreads();
    }
  }

  float* base = Mpart + ((size_t)(bid * NH + h)) * 1024;
#pragma unroll
  for (int dt = 0; dt < 2; ++dt)
#pragma unroll
    for (int et = 0; et < 2; ++et)
#pragma unroll
      for (int r = 0; r < 4; ++r) {
        const int d = dt * 16 + qq * 4 + r;
        const int e = et * 16 + cm;
        base[d * 32 + e] = ctx[dt][et][r];
      }
}

// ---------------------------------------------------------------------------
// Reduce 64 chunk partials + inline fp16-W compensation, scale, softmax over
// d (axis -2); emit S as f16 in MFMA B-fragment layout Sf[mat][h][e][d].
// Grid 64 = mat*8 + h ; block 256.
// ---------------------------------------------------------------------------
__global__ __launch_bounds__(256) void redsm_kernel(
    const float* __restrict__ Mpart,
    const float* __restrict__ Wr, const float* __restrict__ Wx,
    _Float16* __restrict__ Sf)
{
  __shared__ float sl[32 * 33];
  const int bid = blockIdx.x;              // mat*8 + h
  const int h   = bid & 7;
  const int mat = bid >> 3;
  const int s   = mat >> 2;
  const int t   = threadIdx.x;
  const int d   = t >> 3;                  // 0..31
  const int eg  = t & 7;                   // 4 e's

  // inline W-rounding compensation: 16384 * (wk·wv − fp16(wk)·fp16(wv))
  const float* __restrict__ W = (s == 0 ? Wr : Wx);
  const float* wk = W + (size_t)(h * HD + d) * CD;
  float cacc[4] = {0.f, 0.f, 0.f, 0.f};
  for (int cq = 0; cq < 64; ++cq) {
    f32x4 k4 = *(const f32x4*)(wk + cq * 4);
    f32x4 kh4;
#pragma unroll
    for (int j = 0; j < 4; ++j) kh4[j] = (float)(_Float16)k4[j];
#pragma unroll
    for (int j = 0; j < 4; ++j) {
      const int e = eg * 4 + j;
      f32x4 v4 = *(const f32x4*)(W + (size_t)(CD + h * HD + e) * CD + cq * 4);
      f32x4 vh4;
#pragma unroll
      for (int r = 0; r < 4; ++r) vh4[r] = (float)(_Float16)v4[r];
      f32x4 p = k4 * v4 - kh4 * vh4;
      cacc[j] += p[0] + p[1] + p[2] + p[3];
    }
  }

  const int flat = t * 4;
  f32x4 acc;
#pragma unroll
  for (int j = 0; j < 4; ++j) acc[j] = 16384.f * cacc[j];
  const float* base = Mpart + ((size_t)(mat * 64) * NH + h) * 1024 + flat;
#pragma unroll
  for (int p = 0; p < 64; ++p) acc += *(const f32x4*)(base + (size_t)p * NH * 1024);

  const int e0 = flat & 31;
#pragma unroll
  for (int j = 0; j < 4; ++j) sl[d * 33 + e0 + j] = acc[j] * SCALE;
  __syncthreads();

  if (t < 32) {
    const int ee = t;
    float m = -1e30f;
#pragma unroll
    for (int dd = 0; dd < 32; ++dd) m = fmaxf(m, sl[dd * 33 + ee]);
    float ex[32];
    float sum = 0.f;
#pragma unroll
    for (int dd = 0; dd < 32; ++dd) { ex[dd] = __expf(sl[dd * 33 + ee] - m); sum += ex[dd]; }
    const float inv = 1.f / sum;
    _Float16* outp = Sf + (size_t)bid * 1024 + ee * 32;   // [e][d], d contiguous
#pragma unroll
    for (int dq = 0; dq < 4; ++dq) {
      f16x8 pk;
#pragma unroll
      for (int j = 0; j < 8; ++j) pk[j] = (_Float16)(ex[dq * 8 + j] * inv);
      *(f16x8*)(outp + dq * 8) = pk;
    }
  }
}

// ---------------------------------------------------------------------------
// out_s = q_s @ blockdiag(S_{1-s}) — dense-I/O version.
// Grid 2048 = 64-row tiles; block 256 (4 waves), 2 blocks/CU (66.6 KB LDS).
// global(dense 1KB/wave-instr) -> LDS f16 (swizzled) -> MFMA frags ->
// acc -> LDS f32 (pad 260) -> dense dwordx4 stores.
// ---------------------------------------------------------------------------
__global__ __launch_bounds__(256, 2) void out_kernel(
    const float* __restrict__ rgb, const float* __restrict__ xin,
    const _Float16* __restrict__ Sf, float* __restrict__ out)
{
  __shared__ __align__(16) float lds_f[64 * 260];
  _Float16* lds_h = (_Float16*)lds_f;

  const int bid  = blockIdx.x;             // 0..2047
  const int t    = threadIdx.x;
  const int lane = t & 63;
  const int wv   = t >> 6;
  const int cm   = lane & 15;
  const int qq   = lane >> 4;

  const int s  = bid >> 10;
  const int b  = (bid >> 8) & 3;
  const int R0 = (bid & 255) * 64;         // row within (s,b)

  const float* __restrict__ src = (s == 0 ? rgb : xin) + (size_t)b * NTOK * CD;
  float* __restrict__ dst = out + (size_t)s * (4ull * NTOK * CD) + (size_t)b * NTOK * CD;

  // B fragments for the 8 heads of the OTHER stream (L2-resident)
  f16x8 bf[8][2];
#pragma unroll
  for (int h = 0; h < 8; ++h) {
    const _Float16* sm = Sf + (size_t)(((1 - s) * 4 + b) * NH + h) * 1024;
#pragma unroll
    for (int et = 0; et < 2; ++et)
      bf[h][et] = *(const f16x8*)&sm[(et * 16 + cm) * 32 + qq * 8];
  }

  // phase 1: dense global -> LDS f16 (octet XOR swizzle)
  const f32x4* srcv = (const f32x4*)src + (size_t)R0 * 64;
#pragma unroll
  for (int l = 0; l < 16; ++l) {
    const int f   = l * 256 + t;           // 0..4095 over 64 rows x 64 f32x4
    const int row = f >> 6;
    const int c4  = f & 63;
    f32x4 q = srcv[f];
    f16x4 p;
#pragma unroll
    for (int j = 0; j < 4; ++j) p[j] = (_Float16)q[j];
    const int ad = row * 256 + ((((c4 >> 1) ^ (row & 7)) << 3) | ((c4 & 1) * 4));
    *(f16x4*)&lds_h[ad] = p;
  }
  __syncthreads();

  // phase 2a: A fragments for all 8 heads (rows wv*16+cm, k = h*32+qq*8..+7)
  f16x8 af[8];
  const int arow = wv * 16 + cm;
#pragma unroll
  for (int h = 0; h < 8; ++h) {
    const int oct = h * 4 + qq;
    af[h] = *(const f16x8*)&lds_h[arow * 256 + ((oct ^ (arow & 7)) << 3)];
  }
  __syncthreads();   // all frag reads done before LDS reuse

  // phase 2b: MFMA + acc -> LDS f32 tile [64][260]
#pragma unroll
  for (int h = 0; h < 8; ++h) {
    f32x4 a0 = (f32x4){0.f, 0.f, 0.f, 0.f};
    f32x4 a1 = (f32x4){0.f, 0.f, 0.f, 0.f};
    a0 = __builtin_amdgcn_mfma_f32_16x16x32_f16(af[h], bf[h][0], a0, 0, 0, 0);
    a1 = __builtin_amdgcn_mfma_f32_16x16x32_f16(af[h], bf[h][1], a1, 0, 0, 0);
#pragma unroll
    for (int r = 0; r < 4; ++r) {
      const int row = wv * 16 + qq * 4 + r;
      lds_f[row * 260 + h * 32 + cm]      = a0[r];
      lds_f[row * 260 + h * 32 + 16 + cm] = a1[r];
    }
  }
  __syncthreads();

  // phase 3: dense LDS -> global (dwordx4, 1KB per wave-instr)
  f32x4* dstv = (f32x4*)dst + (size_t)R0 * 64;
#pragma unroll
  for (int l = 0; l < 16; ++l) {
    const int f   = l * 256 + t;
    const int row = f >> 6;
    const int c4  = f & 63;
    dstv[f] = *(const f32x4*)&lds_f[row * 260 + c4 * 4];
  }
}

// ---------------------------------------------------------------------------
extern "C" void kernel_launch(void* const* d_in, const int* in_sizes, int n_in,
                              void* d_out, int out_size, void* d_ws, size_t ws_size,
                              hipStream_t stream) {
  const float* rgb = (const float*)d_in[0];
  const float* xin = (const float*)d_in[1];
  const float* Wr  = (const float*)d_in[2];
  const float* Wx  = (const float*)d_in[3];
  float* out = (float*)d_out;

  // Mpart (16.8 MB) lives in d_out scratch: redsm consumes it before
  // out_kernel overwrites every element of d_out (stream-ordered).
  float*     Mpart = (float*)d_out;                 // 512*8*1024 floats
  _Float16*  Sf    = (_Float16*)d_ws;               // 64*1024 halfs = 128 KB

  hipLaunchKernelGGL(kvctx_kernel, dim3(512),  dim3(512), 0, stream,
                     rgb, xin, Wr, Wx, Mpart);
  hipLaunchKernelGGL(redsm_kernel, dim3(64),   dim3(256), 0, stream,
                     Mpart, Wr, Wx, Sf);
  hipLaunchKernelGGL(out_kernel,   dim3(2048), dim3(256), 0, stream,
                     rgb, xin, Sf, out);
}

// Round 7
// 118.111 us; speedup vs baseline: 1.2492x; 1.2492x over previous
//
#include <hip/hip_runtime.h>

#define NTOK 16384
#define CD   256
#define NH   8
#define HD   32
#define SCALE 0.17677669529663687f

typedef float    f32x4 __attribute__((ext_vector_type(4)));
typedef _Float16 f16x8 __attribute__((ext_vector_type(8)));
typedef _Float16 f16x4 __attribute__((ext_vector_type(4)));

__device__ __forceinline__ int a_addr(int n, int c) {
  return n * 256 + ((((c >> 3) ^ (n & 7)) << 3) | (c & 7));
}

// ---------------------------------------------------------------------------
// W prep: convert W (f32) to f16 MFMA fragments, laid out so kvctx can load
// them with dense b128 reads:  Wf[(s*8+h)*4+jt][ct][lane] (f16x8 each).
// jt 0..1 = K rows (h*32 + jt*16 + cm), jt 2..3 = V rows (CD + ...).
// Grid 16 = s*8+h, block 256 (t>>6 = jt, t&63 = lane).
// ---------------------------------------------------------------------------
__global__ __launch_bounds__(256) void wprep_kernel(
    const float* __restrict__ Wr, const float* __restrict__ Wx,
    _Float16* __restrict__ Wf)
{
  const int bid = blockIdx.x;              // s*8 + h
  const int s   = bid >> 3;
  const int h   = bid & 7;
  const float* __restrict__ W = (s == 0 ? Wr : Wx);
  const int t    = threadIdx.x;
  const int jt   = t >> 6;
  const int lane = t & 63;
  const int cm   = lane & 15;
  const int qq   = lane >> 4;

  const int wrow = (jt < 2) ? (h * HD + jt * 16 + cm)
                            : (CD + h * HD + (jt - 2) * 16 + cm);
  const float* wp = W + (size_t)wrow * CD;
  _Float16* dst = Wf + (((size_t)(bid * 4 + jt) * 8) * 64 + lane) * 8;
#pragma unroll
  for (int ct = 0; ct < 8; ++ct) {
    f32x4 w0 = *(const f32x4*)(wp + ct * 32 + qq * 8);
    f32x4 w1 = *(const f32x4*)(wp + ct * 32 + qq * 8 + 4);
    f16x8 f;
#pragma unroll
    for (int j = 0; j < 4; ++j) { f[j] = (_Float16)w0[j]; f[4 + j] = (_Float16)w1[j]; }
    *(f16x8*)(dst + (size_t)ct * 64 * 8) = f;
  }
}

// ---------------------------------------------------------------------------
// Fused KV-projection + per-head context partials (fp16 MFMA).
//   ctx_h(b) = K_hᵀ V_h,  K = A Wkᵀ, V = A Wvᵀ
// Grid 256 = 8 mats x 32 chunks (512 rows); block 512 = 8 waves, wave = head.
// __launch_bounds__(512,1): 256-VGPR budget so wfrag[4][8] (128 VGPR) stays
// RESIDENT — at (512,2) the compiler reloaded W from global every slab
// (VGPR_Count=112 < 128 needed), the round-4..6 stall source.
// Partials -> Mpart (= d_out scratch, consumed by redsm before out_kernel).
// ---------------------------------------------------------------------------
__global__ __launch_bounds__(512, 1) void kvctx_kernel(
    const float* __restrict__ rgb, const float* __restrict__ xin,
    const _Float16* __restrict__ Wf, float* __restrict__ Mpart)
{
  __shared__ __align__(16) _Float16 Ah[2][32 * 256];
  __shared__ __align__(16) _Float16 KVl[8][64 * 40];

  const int bid   = blockIdx.x;
  const int mat   = bid >> 5;              // s*4 + b
  const int chunk = bid & 31;              // 512-row chunk
  const int s     = mat >> 2;
  const float* __restrict__ A =
      (s == 0 ? rgb : xin) + (size_t)(mat & 3) * (NTOK * CD) + (size_t)chunk * 512 * CD;

  const int t    = threadIdx.x;
  const int lane = t & 63;
  const int h    = t >> 6;                 // wave index = head
  const int cm   = lane & 15;
  const int qq   = lane >> 4;

  f32x4 v[4];
  auto issue_loads = [&](int sl) {
#pragma unroll
    for (int i = 0; i < 4; ++i)
      v[i] = *(const f32x4*)(A + (size_t)(sl * 32 + i * 8 + h) * CD + lane * 4);
  };
  auto stage = [&](int buf) {
#pragma unroll
    for (int i = 0; i < 4; ++i) {
      const int n = i * 8 + h;
      const int c = lane * 4;
      f16x4 p;
#pragma unroll
      for (int j = 0; j < 4; ++j) p[j] = (_Float16)v[i][j];
      *(f16x4*)&Ah[buf][a_addr(n, c)] = p;
    }
  };

  issue_loads(0);

  // dense b128 fragment loads (1 KB per wave-instruction), stay resident
  f16x8 wfrag[4][8];
  {
    const _Float16* wsrc = Wf + (((size_t)(s * 8 + h) * 4) * 8 * 64) * 8;
#pragma unroll
    for (int jt = 0; jt < 4; ++jt)
#pragma unroll
      for (int ct = 0; ct < 8; ++ct)
        wfrag[jt][ct] = *(const f16x8*)(wsrc + (((size_t)jt * 8 + ct) * 64 + lane) * 8);
  }

  stage(0);
  __syncthreads();

  f32x4 ctx[2][2];
#pragma unroll
  for (int i = 0; i < 2; ++i)
#pragma unroll
    for (int j = 0; j < 2; ++j) ctx[i][j] = (f32x4){0.f, 0.f, 0.f, 0.f};

  _Float16* KW = KVl[h];

#pragma unroll 1
  for (int sl = 0; sl < 16; ++sl) {
    const int cur = sl & 1;
    if (sl < 15) issue_loads(sl + 1);

    // GEMM1: KV[32 n x 64 j] = A_slab x Wᵀ
    f32x4 kv[2][4];
#pragma unroll
    for (int nt = 0; nt < 2; ++nt)
#pragma unroll
      for (int jt = 0; jt < 4; ++jt) kv[nt][jt] = (f32x4){0.f, 0.f, 0.f, 0.f};
#pragma unroll
    for (int ct = 0; ct < 8; ++ct) {
      f16x8 ah[2];
#pragma unroll
      for (int nt = 0; nt < 2; ++nt) {
        const int row = nt * 16 + cm;
        const int ad  = row * 256 + (((ct * 4 + qq) ^ (row & 7)) << 3);
        ah[nt] = *(const f16x8*)&Ah[cur][ad];
      }
#pragma unroll
      for (int nt = 0; nt < 2; ++nt)
#pragma unroll
        for (int jt = 0; jt < 4; ++jt)
          kv[nt][jt] = __builtin_amdgcn_mfma_f32_16x16x32_f16(ah[nt], wfrag[jt][ct], kv[nt][jt], 0, 0, 0);
    }

    // KV -> wave-private LDS, [j][n] layout
#pragma unroll
    for (int nt = 0; nt < 2; ++nt)
#pragma unroll
      for (int jt = 0; jt < 4; ++jt) {
        const int jj = jt * 16 + cm;
        const int ad = jj * 40 + nt * 16 + qq * 4;
        f16x4 p;
#pragma unroll
        for (int r = 0; r < 4; ++r) p[r] = (_Float16)kv[nt][jt][r];
        *(f16x4*)&KW[ad] = p;
      }

    // GEMM2: ctx[d][e] += Σ_n K[n,d] V[n,e]
    f16x8 kf[2], vf[2];
#pragma unroll
    for (int dt = 0; dt < 2; ++dt)
      kf[dt] = *(const f16x8*)&KW[(dt * 16 + cm) * 40 + qq * 8];
#pragma unroll
    for (int et = 0; et < 2; ++et)
      vf[et] = *(const f16x8*)&KW[(32 + et * 16 + cm) * 40 + qq * 8];
#pragma unroll
    for (int dt = 0; dt < 2; ++dt)
#pragma unroll
      for (int et = 0; et < 2; ++et)
        ctx[dt][et] = __builtin_amdgcn_mfma_f32_16x16x32_f16(kf[dt], vf[et], ctx[dt][et], 0, 0, 0);

    if (sl < 15) {
      stage(cur ^ 1);
      __syncthreads();
    }
  }

  float* base = Mpart + ((size_t)(bid * NH + h)) * 1024;
#pragma unroll
  for (int dt = 0; dt < 2; ++dt)
#pragma unroll
    for (int et = 0; et < 2; ++et)
#pragma unroll
      for (int r = 0; r < 4; ++r) {
        const int d = dt * 16 + qq * 4 + r;
        const int e = et * 16 + cm;
        base[d * 32 + e] = ctx[dt][et][r];
      }
}

// ---------------------------------------------------------------------------
// Reduce 32 chunk partials + inline fp16-W compensation, scale, softmax over
// d (axis -2); emit S as f16 in MFMA B-fragment layout Sf[mat][h][e][d].
// Grid 64 = mat*8 + h ; block 256.
// Corr[d,e] = 16384 * (wk·wv − fp16(wk)·fp16(wv))  — G ≈ N·I term.
// ---------------------------------------------------------------------------
__global__ __launch_bounds__(256) void redsm_kernel(
    const float* __restrict__ Mpart,
    const float* __restrict__ Wr, const float* __restrict__ Wx,
    _Float16* __restrict__ Sf)
{
  __shared__ float sl[32 * 33];
  const int bid = blockIdx.x;              // mat*8 + h
  const int h   = bid & 7;
  const int mat = bid >> 3;
  const int s   = mat >> 2;
  const int t   = threadIdx.x;
  const int d   = t >> 3;                  // 0..31
  const int eg  = t & 7;                   // 4 e's

  const float* __restrict__ W = (s == 0 ? Wr : Wx);
  const float* wk = W + (size_t)(h * HD + d) * CD;
  float cacc[4] = {0.f, 0.f, 0.f, 0.f};
  for (int cq = 0; cq < 64; ++cq) {
    f32x4 k4 = *(const f32x4*)(wk + cq * 4);
    f32x4 kh4;
#pragma unroll
    for (int j = 0; j < 4; ++j) kh4[j] = (float)(_Float16)k4[j];
#pragma unroll
    for (int j = 0; j < 4; ++j) {
      const int e = eg * 4 + j;
      f32x4 v4 = *(const f32x4*)(W + (size_t)(CD + h * HD + e) * CD + cq * 4);
      f32x4 vh4;
#pragma unroll
      for (int r = 0; r < 4; ++r) vh4[r] = (float)(_Float16)v4[r];
      f32x4 p = k4 * v4 - kh4 * vh4;
      cacc[j] += p[0] + p[1] + p[2] + p[3];
    }
  }

  const int flat = t * 4;
  f32x4 acc;
#pragma unroll
  for (int j = 0; j < 4; ++j) acc[j] = 16384.f * cacc[j];
  const float* base = Mpart + ((size_t)(mat * 32) * NH + h) * 1024 + flat;
#pragma unroll
  for (int p = 0; p < 32; ++p) acc += *(const f32x4*)(base + (size_t)p * NH * 1024);

  const int e0 = flat & 31;
#pragma unroll
  for (int j = 0; j < 4; ++j) sl[d * 33 + e0 + j] = acc[j] * SCALE;
  __syncthreads();

  if (t < 32) {
    const int ee = t;
    float m = -1e30f;
#pragma unroll
    for (int dd = 0; dd < 32; ++dd) m = fmaxf(m, sl[dd * 33 + ee]);
    float ex[32];
    float sum = 0.f;
#pragma unroll
    for (int dd = 0; dd < 32; ++dd) { ex[dd] = __expf(sl[dd * 33 + ee] - m); sum += ex[dd]; }
    const float inv = 1.f / sum;
    _Float16* outp = Sf + (size_t)bid * 1024 + ee * 32;   // [e][d], d contiguous
#pragma unroll
    for (int dq = 0; dq < 4; ++dq) {
      f16x8 pk;
#pragma unroll
      for (int j = 0; j < 8; ++j) pk[j] = (_Float16)(ex[dq * 8 + j] * inv);
      *(f16x8*)(outp + dq * 8) = pk;
    }
  }
}

// ---------------------------------------------------------------------------
// out_s = q_s @ blockdiag(S_{1-s}) — dense-I/O version (round-6, verified).
// Grid 2048 = 64-row tiles; block 256 (4 waves), 2 blocks/CU.
// ---------------------------------------------------------------------------
__global__ __launch_bounds__(256, 2) void out_kernel(
    const float* __restrict__ rgb, const float* __restrict__ xin,
    const _Float16* __restrict__ Sf, float* __restrict__ out)
{
  __shared__ __align__(16) float lds_f[64 * 260];
  _Float16* lds_h = (_Float16*)lds_f;

  const int bid  = blockIdx.x;             // 0..2047
  const int t    = threadIdx.x;
  const int lane = t & 63;
  const int wv   = t >> 6;
  const int cm   = lane & 15;
  const int qq   = lane >> 4;

  const int s  = bid >> 10;
  const int b  = (bid >> 8) & 3;
  const int R0 = (bid & 255) * 64;         // row within (s,b)

  const float* __restrict__ src = (s == 0 ? rgb : xin) + (size_t)b * NTOK * CD;
  float* __restrict__ dst = out + (size_t)s * (4ull * NTOK * CD) + (size_t)b * NTOK * CD;

  f16x8 bf[8][2];
#pragma unroll
  for (int h = 0; h < 8; ++h) {
    const _Float16* sm = Sf + (size_t)(((1 - s) * 4 + b) * NH + h) * 1024;
#pragma unroll
    for (int et = 0; et < 2; ++et)
      bf[h][et] = *(const f16x8*)&sm[(et * 16 + cm) * 32 + qq * 8];
  }

  // phase 1: dense global -> LDS f16 (octet XOR swizzle)
  const f32x4* srcv = (const f32x4*)src + (size_t)R0 * 64;
#pragma unroll
  for (int l = 0; l < 16; ++l) {
    const int f   = l * 256 + t;
    const int row = f >> 6;
    const int c4  = f & 63;
    f32x4 q = srcv[f];
    f16x4 p;
#pragma unroll
    for (int j = 0; j < 4; ++j) p[j] = (_Float16)q[j];
    const int ad = row * 256 + ((((c4 >> 1) ^ (row & 7)) << 3) | ((c4 & 1) * 4));
    *(f16x4*)&lds_h[ad] = p;
  }
  __syncthreads();

  // phase 2a: A fragments for all 8 heads
  f16x8 af[8];
  const int arow = wv * 16 + cm;
#pragma unroll
  for (int h = 0; h < 8; ++h) {
    const int oct = h * 4 + qq;
    af[h] = *(const f16x8*)&lds_h[arow * 256 + ((oct ^ (arow & 7)) << 3)];
  }
  __syncthreads();

  // phase 2b: MFMA + acc -> LDS f32 tile [64][260]
#pragma unroll
  for (int h = 0; h < 8; ++h) {
    f32x4 a0 = (f32x4){0.f, 0.f, 0.f, 0.f};
    f32x4 a1 = (f32x4){0.f, 0.f, 0.f, 0.f};
    a0 = __builtin_amdgcn_mfma_f32_16x16x32_f16(af[h], bf[h][0], a0, 0, 0, 0);
    a1 = __builtin_amdgcn_mfma_f32_16x16x32_f16(af[h], bf[h][1], a1, 0, 0, 0);
#pragma unroll
    for (int r = 0; r < 4; ++r) {
      const int row = wv * 16 + qq * 4 + r;
      lds_f[row * 260 + h * 32 + cm]      = a0[r];
      lds_f[row * 260 + h * 32 + 16 + cm] = a1[r];
    }
  }
  __syncthreads();

  // phase 3: dense LDS -> global
  f32x4* dstv = (f32x4*)dst + (size_t)R0 * 64;
#pragma unroll
  for (int l = 0; l < 16; ++l) {
    const int f   = l * 256 + t;
    const int row = f >> 6;
    const int c4  = f & 63;
    dstv[f] = *(const f32x4*)&lds_f[row * 260 + c4 * 4];
  }
}

// ---------------------------------------------------------------------------
extern "C" void kernel_launch(void* const* d_in, const int* in_sizes, int n_in,
                              void* d_out, int out_size, void* d_ws, size_t ws_size,
                              hipStream_t stream) {
  const float* rgb = (const float*)d_in[0];
  const float* xin = (const float*)d_in[1];
  const float* Wr  = (const float*)d_in[2];
  const float* Wx  = (const float*)d_in[3];
  float* out = (float*)d_out;

  // Mpart (8 MB) lives in d_out scratch: redsm consumes it before out_kernel
  // overwrites every element of d_out (stream-ordered, deterministic).
  float*     Mpart = (float*)d_out;                 // 256*8*1024 floats
  _Float16*  Sf    = (_Float16*)d_ws;               // 64*1024 halfs  = 128 KB
  _Float16*  Wf    = Sf + 64 * 1024;                // 16*4*8*64*8    = 512 KB

  hipLaunchKernelGGL(wprep_kernel, dim3(16),   dim3(256), 0, stream, Wr, Wx, Wf);
  hipLaunchKernelGGL(kvctx_kernel, dim3(256),  dim3(512), 0, stream,
                     rgb, xin, Wf, Mpart);
  hipLaunchKernelGGL(redsm_kernel, dim3(64),   dim3(256), 0, stream,
                     Mpart, Wr, Wx, Sf);
  hipLaunchKernelGGL(out_kernel,   dim3(2048), dim3(256), 0, stream,
                     rgb, xin, Sf, out);
}